// Round 12
// baseline (286.911 us; speedup 1.0000x reference)
//
#include <hip/hip_runtime.h>
#include <hip/hip_bf16.h>

#define NEG_SLOPE 0.2f

typedef __attribute__((ext_vector_type(8))) short short8v;
typedef __attribute__((ext_vector_type(4))) float f32x4;

__device__ __forceinline__ float wave_max64(float v) {
    for (int o = 32; o; o >>= 1) v = fmaxf(v, __shfl_xor(v, o));
    return v;
}
__device__ __forceinline__ float wave_sum64(float v) {
    for (int o = 32; o; o >>= 1) v += __shfl_xor(v, o);
    return v;
}
__device__ __forceinline__ unsigned short f2bf(float f) {
    unsigned int u = __float_as_uint(f);
    unsigned int r = (u + 0x7fffu + ((u >> 16) & 1u)) >> 16;
    return (unsigned short)r;
}
__device__ __forceinline__ float bf2f(unsigned short u) {
    return __uint_as_float(((unsigned int)u) << 16);
}
__device__ __forceinline__ float bflo(unsigned int pk) {
    return __uint_as_float(pk << 16);
}
__device__ __forceinline__ float bfhi(unsigned int pk) {
    return __uint_as_float(pk & 0xFFFF0000u);
}

// ---------------- edge histogram: 4-way split counters (contention /4) ----------------

__global__ __launch_bounds__(256) void k_hist(const int* __restrict__ dst,
                                              int* __restrict__ deg4,
                                              int* __restrict__ rank, int E, int n) {
    int e = blockIdx.x * 256 + threadIdx.x;
    if (e < E) {
        int c = e & 3;
        rank[e] = atomicAdd(&deg4[(size_t)c * n + dst[e]], 1);
    }
}

// ---------------- parallel 3-phase exclusive scan of total deg -> row_start, per-copy coff ----

__global__ __launch_bounds__(256) void k_scan1(const int* __restrict__ deg4,
                                               int* __restrict__ bsum, int n) {
    int idx = blockIdx.x * 256 + threadIdx.x;
    int v = 0;
    if (idx < n)
        v = deg4[idx] + deg4[n + idx] + deg4[2 * (size_t)n + idx] + deg4[3 * (size_t)n + idx];
    for (int o = 32; o; o >>= 1) v += __shfl_xor(v, o);
    __shared__ int ws[4];
    if ((threadIdx.x & 63) == 0) ws[threadIdx.x >> 6] = v;
    __syncthreads();
    if (threadIdx.x == 0) bsum[blockIdx.x] = ws[0] + ws[1] + ws[2] + ws[3];
}

__global__ __launch_bounds__(256) void k_scan2(const int* __restrict__ bsum,
                                               int* __restrict__ bpre,
                                               int* __restrict__ row_start,
                                               int nb, int n) {
    __shared__ int s[256];
    int t = threadIdx.x;
    int v = t < nb ? bsum[t] : 0;
    s[t] = v;
    __syncthreads();
    for (int o = 1; o < 256; o <<= 1) {
        int u = (t >= o) ? s[t - o] : 0;
        __syncthreads();
        s[t] += u;
        __syncthreads();
    }
    if (t < nb) bpre[t] = s[t] - v;
    if (t == 255) row_start[n] = s[255];
}

__global__ __launch_bounds__(256) void k_scan3(const int* __restrict__ deg4,
                                               const int* __restrict__ bpre,
                                               int* __restrict__ row_start,
                                               int* __restrict__ coff, int n) {
    int idx = blockIdx.x * 256 + threadIdx.x;
    int lane = threadIdx.x & 63;
    int w = threadIdx.x >> 6;
    int d0 = 0, d1 = 0, d2 = 0, d3 = 0;
    if (idx < n) {
        d0 = deg4[idx];
        d1 = deg4[(size_t)n + idx];
        d2 = deg4[2 * (size_t)n + idx];
        d3 = deg4[3 * (size_t)n + idx];
    }
    int d = d0 + d1 + d2 + d3;
    int x = d;
    for (int o = 1; o < 64; o <<= 1) {
        int u = __shfl_up(x, o);
        if (lane >= o) x += u;
    }
    __shared__ int ws[4];
    if (lane == 63) ws[w] = x;
    __syncthreads();
    int add = bpre[blockIdx.x];
    for (int i = 0; i < w; i++) add += ws[i];
    if (idx < n) {
        int base = add + x - d;  // exclusive prefix
        row_start[idx] = base;
        coff[idx] = base;
        coff[(size_t)n + idx] = base + d0;
        coff[2 * (size_t)n + idx] = base + d0 + d1;
        coff[3 * (size_t)n + idx] = base + d0 + d1 + d2;
    }
}

// ---------------- scatter (atomic-free via per-copy offsets + rank) ----------------

__global__ void k_scatter(const int* __restrict__ dst, const int* __restrict__ src,
                          const int* __restrict__ rank, const int* __restrict__ coff,
                          int* __restrict__ ssrc, int E, int n) {
    int e = blockIdx.x * blockDim.x + threadIdx.x;
    if (e < E) {
        int c = e & 3;
        int pos = coff[(size_t)c * n + dst[e]] + rank[e];
        ssrc[pos] = src[e];
    }
}

// ---------------- Layer 1 GEMM: z1(bf16) = feat @ W1, fused el1/er1, W2-prep ----------------

__global__ __launch_bounds__(256) void k_gemm1(const float* __restrict__ feat,
                                               const float* __restrict__ W1,
                                               const float* __restrict__ al,
                                               const float* __restrict__ ar,
                                               const float* __restrict__ W2,
                                               unsigned short* __restrict__ W2T,
                                               unsigned short* __restrict__ z1,
                                               float4* __restrict__ el1,
                                               float4* __restrict__ er1, int n) {
    for (int idx = blockIdx.x * 256 + threadIdx.x; idx < 96 * 192; idx += gridDim.x * 256) {
        int c = idx / 96, k = idx - c * 96;
        W2T[idx] = f2bf(W2[k * 192 + c]);
    }
    __shared__ float sW[960], sal[96], sar[96];
    for (int i = threadIdx.x; i < 960; i += 256) sW[i] = W1[i];
    for (int i = threadIdx.x; i < 96; i += 256) { sal[i] = al[i]; sar[i] = ar[i]; }
    __syncthreads();
    int nd = blockIdx.x * 256 + threadIdx.x;
    if (nd >= n) return;
    float x[10];
#pragma unroll
    for (int k = 0; k < 10; k++) x[k] = feat[(size_t)nd * 10 + k];
    float el[3] = {0.f, 0.f, 0.f}, er[3] = {0.f, 0.f, 0.f};
#pragma unroll
    for (int h = 0; h < 3; h++) {
#pragma unroll
        for (int d0 = 0; d0 < 32; d0 += 4) {
            ushort4 o;
            unsigned short* op = &o.x;
#pragma unroll
            for (int q = 0; q < 4; q++) {
                int c = h * 32 + d0 + q;
                float acc = 0.f;
#pragma unroll
                for (int k = 0; k < 10; k++) acc += x[k] * sW[k * 96 + c];
                op[q] = f2bf(acc);
                el[h] += acc * sal[c];
                er[h] += acc * sar[c];
            }
            *reinterpret_cast<ushort4*>(&z1[(size_t)nd * 96 + h * 32 + d0]) = o;
        }
    }
    el1[nd] = make_float4(el[0], el[1], el[2], 0.f);
    er1[nd] = make_float4(er[0], er[1], er[2], 0.f);
}

// ---------------- GAT aggregation: wave per dst node; bf16 in/out; 8-deep batched gathers ----------------

template <int D, int VW>
__global__ __launch_bounds__(256) void k_agg(const unsigned short* __restrict__ z,
                                             const float4* __restrict__ el,
                                             const float4* __restrict__ er,
                                             const int* __restrict__ row_start,
                                             const int* __restrict__ ssrc,
                                             unsigned short* __restrict__ xout, int n) {
    constexpr int H = 3;
    constexpr int HD = H * D;
    constexpr int NL = HD / VW;  // 48
    __shared__ float pl[4][272];
    int wid = (blockIdx.x * blockDim.x + threadIdx.x) >> 6;
    int lane = threadIdx.x & 63;
    int w = threadIdx.x >> 6;
    if (wid >= n) return;
    int s0 = row_start[wid];
    int deg = row_start[wid + 1] - s0;
    unsigned short* orow = xout + (size_t)wid * HD;
    if (deg <= 0) {
        if (lane < NL) {
            if constexpr (VW == 2)
                *reinterpret_cast<ushort2*>(orow + VW * lane) = make_ushort2(0, 0);
            else
                *reinterpret_cast<ushort4*>(orow + VW * lane) = make_ushort4(0, 0, 0, 0);
        }
        return;
    }
    float4 erv = er[wid];
    int hh = (VW * lane) / D;
    if (hh >= H) hh = H - 1;

    if (deg <= 64) {
        bool act = lane < deg;
        int sv = act ? ssrc[s0 + lane] : 0;
        float4 elv = el[sv];
        float v0 = elv.x + erv.x; v0 = v0 > 0.f ? v0 : NEG_SLOPE * v0;
        float v1 = elv.y + erv.y; v1 = v1 > 0.f ? v1 : NEG_SLOPE * v1;
        float v2 = elv.z + erv.z; v2 = v2 > 0.f ? v2 : NEG_SLOPE * v2;
        if (!act) { v0 = -3.402823466e38f; v1 = v0; v2 = v0; }
        float m0 = wave_max64(v0), m1 = wave_max64(v1), m2 = wave_max64(v2);
        float p0 = act ? __expf(v0 - m0) : 0.f;
        float p1 = act ? __expf(v1 - m1) : 0.f;
        float p2 = act ? __expf(v2 - m2) : 0.f;
        float i0 = 1.f / (wave_sum64(p0) + 1e-16f);
        float i1 = 1.f / (wave_sum64(p1) + 1e-16f);
        float i2 = 1.f / (wave_sum64(p2) + 1e-16f);
        pl[w][0 * 68 + lane] = p0 * i0;
        pl[w][1 * 68 + lane] = p1 * i1;
        pl[w][2 * 68 + lane] = p2 * i2;
        reinterpret_cast<int*>(&pl[w][204])[lane] = sv * HD;
        const float* pt = &pl[w][hh * 68];
        const int* zt = reinterpret_cast<const int*>(&pl[w][204]);

        int col = VW * (lane < NL ? lane : NL - 1);
        const unsigned short* zc = z + col;
        float acc0 = 0.f, acc1 = 0.f, acc2 = 0.f, acc3 = 0.f;
        int i = 0;
        for (; i + 8 <= deg; i += 8) {
            int zo[8];
#pragma unroll
            for (int j = 0; j < 8; j++) zo[j] = zt[i + j];
            if constexpr (VW == 2) {
                unsigned int r[8];
#pragma unroll
                for (int j = 0; j < 8; j++)
                    r[j] = *reinterpret_cast<const unsigned int*>(zc + zo[j]);
#pragma unroll
                for (int j = 0; j < 8; j++) {
                    float a = pt[i + j];
                    acc0 += a * bflo(r[j]); acc1 += a * bfhi(r[j]);
                }
            } else {
                uint2 r[8];
#pragma unroll
                for (int j = 0; j < 8; j++)
                    r[j] = *reinterpret_cast<const uint2*>(zc + zo[j]);
#pragma unroll
                for (int j = 0; j < 8; j++) {
                    float a = pt[i + j];
                    acc0 += a * bflo(r[j].x); acc1 += a * bfhi(r[j].x);
                    acc2 += a * bflo(r[j].y); acc3 += a * bfhi(r[j].y);
                }
            }
        }
        for (; i < deg; i++) {
            int zo = zt[i];
            float a = pt[i];
            if constexpr (VW == 2) {
                unsigned int zv = *reinterpret_cast<const unsigned int*>(zc + zo);
                acc0 += a * bflo(zv); acc1 += a * bfhi(zv);
            } else {
                uint2 zv = *reinterpret_cast<const uint2*>(zc + zo);
                acc0 += a * bflo(zv.x); acc1 += a * bfhi(zv.x);
                acc2 += a * bflo(zv.y); acc3 += a * bfhi(zv.y);
            }
        }
        if (lane < NL) {
            if constexpr (VW == 2) {
                ushort2 o2;
                o2.x = f2bf(fmaxf(acc0, 0.f)); o2.y = f2bf(fmaxf(acc1, 0.f));
                *reinterpret_cast<ushort2*>(orow + col) = o2;
            } else {
                ushort4 o4;
                o4.x = f2bf(fmaxf(acc0, 0.f)); o4.y = f2bf(fmaxf(acc1, 0.f));
                o4.z = f2bf(fmaxf(acc2, 0.f)); o4.w = f2bf(fmaxf(acc3, 0.f));
                *reinterpret_cast<ushort4*>(orow + col) = o4;
            }
        }
    } else {
        // ---- fallback 3-pass (deg > 64; correctness-only) ----
        float ern[3] = {erv.x, erv.y, erv.z};
        float m[3] = {-3.402823466e38f, -3.402823466e38f, -3.402823466e38f};
        for (int i = lane; i < deg; i += 64) {
            int sv = ssrc[s0 + i];
            float4 elv = el[sv];
            float vv[3] = {elv.x, elv.y, elv.z};
#pragma unroll
            for (int h = 0; h < 3; h++) {
                float v = vv[h] + ern[h];
                v = v > 0.f ? v : NEG_SLOPE * v;
                m[h] = fmaxf(m[h], v);
            }
        }
#pragma unroll
        for (int h = 0; h < 3; h++) m[h] = wave_max64(m[h]);
        float s[3] = {0.f, 0.f, 0.f};
        for (int i = lane; i < deg; i += 64) {
            int sv = ssrc[s0 + i];
            float4 elv = el[sv];
            float vv[3] = {elv.x, elv.y, elv.z};
#pragma unroll
            for (int h = 0; h < 3; h++) {
                float v = vv[h] + ern[h];
                v = v > 0.f ? v : NEG_SLOPE * v;
                s[h] += __expf(v - m[h]);
            }
        }
#pragma unroll
        for (int h = 0; h < 3; h++) s[h] = 1.f / (wave_sum64(s[h]) + 1e-16f);
        constexpr int NC = (HD + 63) / 64;
        float acc[NC];
#pragma unroll
        for (int j = 0; j < NC; j++) acc[j] = 0.f;
        for (int i = 0; i < deg; i++) {
            int sv = ssrc[s0 + i];
            float4 elv = el[sv];
            float vv[3] = {elv.x, elv.y, elv.z};
            float a[3];
#pragma unroll
            for (int h = 0; h < 3; h++) {
                float v = vv[h] + ern[h];
                v = v > 0.f ? v : NEG_SLOPE * v;
                a[h] = __expf(v - m[h]) * s[h];
            }
            const unsigned short* zr = z + (size_t)sv * HD;
#pragma unroll
            for (int j = 0; j < NC; j++) {
                int c = lane + 64 * j;
                if (c < HD) acc[j] += a[c / D] * bf2f(zr[c]);
            }
        }
#pragma unroll
        for (int j = 0; j < NC; j++) {
            int c = lane + 64 * j;
            if (c < HD) orow[c] = f2bf(fmaxf(acc[j], 0.f));
        }
    }
}

// ---------------- Layer 2 GEMM via MFMA: z2(bf16) = x1(bf16) @ W2, fused el2/er2 ----------------

__global__ __launch_bounds__(256) void k_gemm2(const unsigned short* __restrict__ x1,
                                               const unsigned short* __restrict__ W2T,
                                               const float* __restrict__ al,
                                               const float* __restrict__ ar,
                                               unsigned short* __restrict__ z2,
                                               float* __restrict__ el2,
                                               float* __restrict__ er2, int n) {
    int w = threadIdx.x >> 6;
    int l = threadIdx.x & 63;
    int q = l >> 4, c16 = l & 15;
    int Ra = blockIdx.x * 64 + w * 16 + c16;
    short8v afr[3];
    if (Ra < n) {
#pragma unroll
        for (int ks = 0; ks < 3; ks++)
            afr[ks] = *reinterpret_cast<const short8v*>(x1 + (size_t)Ra * 96 + ks * 32 + q * 8);
    } else {
#pragma unroll
        for (int ks = 0; ks < 3; ks++)
#pragma unroll
            for (int i = 0; i < 8; i++) afr[ks][i] = 0;
    }
    f32x4 acc[12];
#pragma unroll
    for (int t = 0; t < 12; t++)
#pragma unroll
        for (int r = 0; r < 4; r++) acc[t][r] = 0.f;
#pragma unroll
    for (int t = 0; t < 12; t++) {
        const unsigned short* bp = W2T + (t * 16 + c16) * 96 + q * 8;
#pragma unroll
        for (int ks = 0; ks < 3; ks++) {
            short8v bfr = *reinterpret_cast<const short8v*>(bp + ks * 32);
            acc[t] = __builtin_amdgcn_mfma_f32_16x16x32_bf16(afr[ks], bfr, acc[t], 0, 0, 0);
        }
    }
    int Rq = blockIdx.x * 64 + w * 16 + q * 4;
    float elp[4][3] = {}, erp[4][3] = {};
#pragma unroll
    for (int t = 0; t < 12; t++) {
        int h = t >> 2;
        float alv = al[t * 16 + c16];
        float arv = ar[t * 16 + c16];
#pragma unroll
        for (int r = 0; r < 4; r++) {
            float v = acc[t][r];
            elp[r][h] += v * alv;
            erp[r][h] += v * arv;
            if (Rq + r < n) z2[(size_t)(Rq + r) * 192 + t * 16 + c16] = f2bf(v);
        }
    }
#pragma unroll
    for (int r = 0; r < 4; r++)
#pragma unroll
        for (int h = 0; h < 3; h++)
#pragma unroll
            for (int o = 1; o < 16; o <<= 1) {
                elp[r][h] += __shfl_xor(elp[r][h], o);
                erp[r][h] += __shfl_xor(erp[r][h], o);
            }
    if (c16 == 0) {
#pragma unroll
        for (int r = 0; r < 4; r++)
            if (Rq + r < n) {
#pragma unroll
                for (int h = 0; h < 3; h++) {
                    el2[(Rq + r) * 4 + h] = elp[r][h];
                    er2[(Rq + r) * 4 + h] = erp[r][h];
                }
            }
    }
}

// ---------------- graph mean-pool (graph_ids sorted): 32-node chunks, x2 bf16 ----------------

__global__ __launch_bounds__(192) void k_pool(const unsigned short* __restrict__ x2,
                                              const int* __restrict__ gid,
                                              float* __restrict__ gsum, int n) {
    int base = blockIdx.x * 32;
    if (base >= n) return;
    int end = base + 32; if (end > n) end = n;
    int c = threadIdx.x;
    float acc = 0.f;
    int gprev = gid[base];
    for (int i = base; i < end; i++) {
        int g = gid[i];
        if (g != gprev) {
            atomicAdd(&gsum[gprev * 192 + c], acc);
            acc = 0.f;
            gprev = g;
        }
        acc += bf2f(x2[(size_t)i * 192 + c]);
    }
    atomicAdd(&gsum[gprev * 192 + c], acc);
}

// ---------------- MLP head: one block per graph; count via inline binary search ----------------

__global__ __launch_bounds__(64) void k_head(const float* __restrict__ gsum,
                                             const int* __restrict__ gid,
                                             const float* __restrict__ d1w,
                                             const float* __restrict__ d1b,
                                             const float* __restrict__ d2w,
                                             const float* __restrict__ d2b,
                                             float* __restrict__ out, int n, int G) {
    int g = blockIdx.x, j = threadIdx.x;
    int lo0 = 0, hi0 = n;
    while (lo0 < hi0) { int mid = (lo0 + hi0) >> 1; if (gid[mid] < g) lo0 = mid + 1; else hi0 = mid; }
    int lo1 = lo0, hi1 = n;
    while (lo1 < hi1) { int mid = (lo1 + hi1) >> 1; if (gid[mid] < g + 1) lo1 = mid + 1; else hi1 = mid; }
    float inv = 1.f / fmaxf((float)(lo1 - lo0), 1.f);
    float h = d1b[j];
    for (int k = 0; k < 192; k++) h += (gsum[g * 192 + k] * inv) * d1w[(size_t)k * 64 + j];
    h = fmaxf(h, 0.f);
    float v = h * d2w[j];
    for (int o = 32; o; o >>= 1) v += __shfl_xor(v, o);
    if (j == 0) out[g] = v + d2b[0];
}

// ---------------- launch ----------------

extern "C" void kernel_launch(void* const* d_in, const int* in_sizes, int n_in,
                              void* d_out, int out_size, void* d_ws, size_t ws_size,
                              hipStream_t stream) {
    const float* feat = (const float*)d_in[0];
    const int* src = (const int*)d_in[1];
    const int* dst = (const int*)d_in[2];
    const int* gid = (const int*)d_in[3];
    const float* W1 = (const float*)d_in[4];
    const float* al1 = (const float*)d_in[5];
    const float* ar1 = (const float*)d_in[6];
    const float* W2 = (const float*)d_in[7];
    const float* al2 = (const float*)d_in[8];
    const float* ar2 = (const float*)d_in[9];
    const float* d1w = (const float*)d_in[10];
    const float* d1b = (const float*)d_in[11];
    const float* d2w = (const float*)d_in[12];
    const float* d2b = (const float*)d_in[13];
    float* out = (float*)d_out;
    const int N = in_sizes[0] / 10;   // 50000
    const int E = in_sizes[1];        // 800000
    const int G = out_size;           // 128
    const int NB = (N + 255) / 256;   // scan blocks (196)

    char* p = (char*)d_ws;
    auto take = [&](size_t bytes) -> char* {
        char* r = p;
        p += (bytes + 255) & ~(size_t)255;
        return r;
    };
    unsigned short* z1 = (unsigned short*)take((size_t)N * 96 * 2);  // 9.6MB
    unsigned short* x1 = (unsigned short*)take((size_t)N * 96 * 2);  // 9.6MB
    unsigned short* x2 = z1;  // aliases z1+x1 (dead when agg2 writes)
    unsigned short* z2 = (unsigned short*)take((size_t)N * 192 * 2);
    float4* el1 = (float4*)take((size_t)N * 16);
    float4* er1 = (float4*)take((size_t)N * 16);
    float* el2 = (float*)take((size_t)N * 16);
    float* er2 = (float*)take((size_t)N * 16);
    unsigned short* W2T = (unsigned short*)take((size_t)96 * 192 * 2);
    int* rank = (int*)take((size_t)E * 4);
    int* coff = (int*)take((size_t)4 * N * 4);
    int* bsum = (int*)take((size_t)NB * 4);
    int* bpre = (int*)take((size_t)NB * 4);
    // single zero-init region: deg4 (4 copies) | gsum
    size_t zbytes = (size_t)4 * N * 4 + (size_t)G * 192 * 4;
    int* deg4 = (int*)take(zbytes);
    float* gsum = (float*)(deg4 + (size_t)4 * N);
    int* row_start = (int*)take((size_t)(N + 1) * 4);
    int* ssrc = (int*)take((size_t)E * 4);

    hipMemsetAsync(deg4, 0, zbytes, stream);

    // Edge histogram (4-way split counters) + rank
    k_hist<<<(E + 255) / 256, 256, 0, stream>>>(dst, deg4, rank, E, N);
    // Layer-1 GEMM + W2 prep
    k_gemm1<<<(N + 255) / 256, 256, 0, stream>>>(feat, W1, al1, ar1, W2, W2T,
                                                 z1, el1, er1, N);
    // CSR finish: parallel scan (+ per-copy offsets) + atomic-free scatter
    k_scan1<<<NB, 256, 0, stream>>>(deg4, bsum, N);
    k_scan2<<<1, 256, 0, stream>>>(bsum, bpre, row_start, NB, N);
    k_scan3<<<NB, 256, 0, stream>>>(deg4, bpre, row_start, coff, N);
    k_scatter<<<(E + 255) / 256, 256, 0, stream>>>(dst, src, rank, coff, ssrc, E, N);

    // Layer 1 aggregation (bf16 out)
    k_agg<32, 2><<<((size_t)N * 64 + 255) / 256, 256, 0, stream>>>(
        z1, el1, er1, row_start, ssrc, x1, N);
    // Layer 2 GEMM (MFMA bf16, fused el2/er2)
    k_gemm2<<<(N + 63) / 64, 256, 0, stream>>>(x1, W2T, al2, ar2, z2, el2, er2, N);
    // Layer 2 aggregation (bf16 out)
    k_agg<64, 4><<<((size_t)N * 64 + 255) / 256, 256, 0, stream>>>(
        z2, (const float4*)el2, (const float4*)er2, row_start, ssrc, x2, N);
    // Pool (data-parallel, 32-node chunks) + head
    k_pool<<<(N + 31) / 32, 192, 0, stream>>>(x2, gid, gsum, N);
    k_head<<<G, 64, 0, stream>>>(gsum, gid, d1w, d1b, d2w, d2b, out, N, G);
}

// Round 14
// 276.340 us; speedup vs baseline: 1.0383x; 1.0383x over previous
//
#include <hip/hip_runtime.h>
#include <hip/hip_bf16.h>

#define NEG_SLOPE 0.2f

typedef __attribute__((ext_vector_type(8))) short short8v;
typedef __attribute__((ext_vector_type(4))) float f32x4;

__device__ __forceinline__ float wave_max64(float v) {
    for (int o = 32; o; o >>= 1) v = fmaxf(v, __shfl_xor(v, o));
    return v;
}
__device__ __forceinline__ float wave_sum64(float v) {
    for (int o = 32; o; o >>= 1) v += __shfl_xor(v, o);
    return v;
}
__device__ __forceinline__ unsigned short f2bf(float f) {
    unsigned int u = __float_as_uint(f);
    unsigned int r = (u + 0x7fffu + ((u >> 16) & 1u)) >> 16;
    return (unsigned short)r;
}
__device__ __forceinline__ float bf2f(unsigned short u) {
    return __uint_as_float(((unsigned int)u) << 16);
}
__device__ __forceinline__ float bflo(unsigned int pk) {
    return __uint_as_float(pk << 16);
}
__device__ __forceinline__ float bfhi(unsigned int pk) {
    return __uint_as_float(pk & 0xFFFF0000u);
}

// ---------------- hist (+rank) + W2T/val2/var2 prep ----------------

__global__ __launch_bounds__(256) void k_hist(const int* __restrict__ dst,
                                              int* __restrict__ deg,
                                              int* __restrict__ rank, int E,
                                              const float* __restrict__ W2,
                                              const float* __restrict__ al2,
                                              const float* __restrict__ ar2,
                                              unsigned short* __restrict__ W2T,
                                              float* __restrict__ val2,
                                              float* __restrict__ var2) {
    int idx = blockIdx.x * 256 + threadIdx.x;
    if (idx < 96 * 192) {
        int c = idx / 96, k = idx - c * 96;
        W2T[idx] = f2bf(W2[k * 192 + c]);       // W2T[c][k] = W2[k][c]
    } else if (idx < 96 * 192 + 2 * 288) {
        int t = idx - 96 * 192;
        int which = t / 288;                     // 0: val2, 1: var2
        int tt = t - which * 288;
        int h = tt / 96, j = tt - h * 96;
        const float* av = which ? ar2 : al2;
        float a = 0.f;
        for (int d = 0; d < 64; d++) a += W2[j * 192 + h * 64 + d] * av[h * 64 + d];
        (which ? var2 : val2)[tt] = a;
    }
    if (idx < E) rank[idx] = atomicAdd(&deg[dst[idx]], 1);
}

// ---------------- parallel 3-phase exclusive scan of deg -> row_start ----------------

__global__ __launch_bounds__(256) void k_scan1(const int* __restrict__ deg,
                                               int* __restrict__ bsum, int n) {
    int idx = blockIdx.x * 256 + threadIdx.x;
    int v = idx < n ? deg[idx] : 0;
    for (int o = 32; o; o >>= 1) v += __shfl_xor(v, o);
    __shared__ int ws[4];
    if ((threadIdx.x & 63) == 0) ws[threadIdx.x >> 6] = v;
    __syncthreads();
    if (threadIdx.x == 0) bsum[blockIdx.x] = ws[0] + ws[1] + ws[2] + ws[3];
}

__global__ __launch_bounds__(256) void k_scan2(const int* __restrict__ bsum,
                                               int* __restrict__ bpre,
                                               int* __restrict__ row_start,
                                               int nb, int n) {
    __shared__ int s[256];
    int t = threadIdx.x;
    int v = t < nb ? bsum[t] : 0;
    s[t] = v;
    __syncthreads();
    for (int o = 1; o < 256; o <<= 1) {
        int u = (t >= o) ? s[t - o] : 0;
        __syncthreads();
        s[t] += u;
        __syncthreads();
    }
    if (t < nb) bpre[t] = s[t] - v;
    if (t == 255) row_start[n] = s[255];
}

__global__ __launch_bounds__(256) void k_scan3(const int* __restrict__ deg,
                                               const int* __restrict__ bpre,
                                               int* __restrict__ row_start, int n) {
    int idx = blockIdx.x * 256 + threadIdx.x;
    int lane = threadIdx.x & 63;
    int w = threadIdx.x >> 6;
    int d = idx < n ? deg[idx] : 0;
    int x = d;
    for (int o = 1; o < 64; o <<= 1) {
        int u = __shfl_up(x, o);
        if (lane >= o) x += u;
    }
    __shared__ int ws[4];
    if (lane == 63) ws[w] = x;
    __syncthreads();
    int add = bpre[blockIdx.x];
    for (int i = 0; i < w; i++) add += ws[i];
    if (idx < n) row_start[idx] = add + x - d;
}

__global__ void k_scatter(const int* __restrict__ dst, const int* __restrict__ src,
                          const int* __restrict__ rank, const int* __restrict__ row_start,
                          int* __restrict__ ssrc, int E) {
    int e = blockIdx.x * blockDim.x + threadIdx.x;
    if (e < E) ssrc[row_start[dst[e]] + rank[e]] = src[e];
}

// ---------------- el1/er1 = feat @ (W1_h . al1_h) ----------------

__global__ __launch_bounds__(256) void k_el1(const float* __restrict__ feat,
                                             const float* __restrict__ W1,
                                             const float* __restrict__ al,
                                             const float* __restrict__ ar,
                                             float4* __restrict__ el1,
                                             float4* __restrict__ er1, int n) {
    __shared__ float sW[960], sal[96], sar[96], sval[30], svar[30];
    for (int i = threadIdx.x; i < 960; i += 256) sW[i] = W1[i];
    for (int i = threadIdx.x; i < 96; i += 256) { sal[i] = al[i]; sar[i] = ar[i]; }
    __syncthreads();
    int t = threadIdx.x;
    if (t < 30) {
        int h = t / 10, k = t - h * 10;
        float a = 0.f, b = 0.f;
        for (int d = 0; d < 32; d++) {
            float wv = sW[k * 96 + h * 32 + d];
            a += wv * sal[h * 32 + d];
            b += wv * sar[h * 32 + d];
        }
        sval[t] = a; svar[t] = b;
    }
    __syncthreads();
    int nd = blockIdx.x * 256 + t;
    if (nd >= n) return;
    float x[10];
#pragma unroll
    for (int k = 0; k < 10; k++) x[k] = feat[(size_t)nd * 10 + k];
    float el[3] = {}, er[3] = {};
#pragma unroll
    for (int h = 0; h < 3; h++)
#pragma unroll
        for (int k = 0; k < 10; k++) {
            el[h] += x[k] * sval[h * 10 + k];
            er[h] += x[k] * svar[h * 10 + k];
        }
    el1[nd] = make_float4(el[0], el[1], el[2], 0.f);
    er1[nd] = make_float4(er[0], er[1], er[2], 0.f);
}

// ---------------- agg1': y1[n][3][10] = sum_e alpha1 * feat[src] ----------------

__global__ __launch_bounds__(256) void k_agg1(const float* __restrict__ feat,
                                              const float4* __restrict__ el,
                                              const float4* __restrict__ er,
                                              const int* __restrict__ row_start,
                                              const int* __restrict__ ssrc,
                                              float* __restrict__ y1, int n) {
    __shared__ float pl[4][272];   // [0..203]: 3x68 alpha; [204..267]: zofs ints
    int wid = (blockIdx.x * blockDim.x + threadIdx.x) >> 6;
    int lane = threadIdx.x & 63;
    int w = threadIdx.x >> 6;
    if (wid >= n) return;
    int s0 = row_start[wid];
    int deg = row_start[wid + 1] - s0;
    if (deg <= 0) {
        if (lane < 30) y1[(size_t)wid * 30 + lane] = 0.f;
        return;
    }
    float4 erv = er[wid];
    // per-lane (h,k) for pass B; lanes ll>=30 mapped to safe (2,9)
    int ll = lane & 31, hf = lane >> 5;
    int h = ll / 10, k = ll - (ll / 10) * 10;
    if (ll >= 30) { h = 2; k = 9; }

    if (deg <= 64) {
        bool act = lane < deg;
        int sv = act ? ssrc[s0 + lane] : 0;
        float4 elv = el[sv];
        float v0 = elv.x + erv.x; v0 = v0 > 0.f ? v0 : NEG_SLOPE * v0;
        float v1 = elv.y + erv.y; v1 = v1 > 0.f ? v1 : NEG_SLOPE * v1;
        float v2 = elv.z + erv.z; v2 = v2 > 0.f ? v2 : NEG_SLOPE * v2;
        if (!act) { v0 = -3.402823466e38f; v1 = v0; v2 = v0; }
        float m0 = wave_max64(v0), m1 = wave_max64(v1), m2 = wave_max64(v2);
        float p0 = act ? __expf(v0 - m0) : 0.f;
        float p1 = act ? __expf(v1 - m1) : 0.f;
        float p2 = act ? __expf(v2 - m2) : 0.f;
        float i0 = 1.f / (wave_sum64(p0) + 1e-16f);
        float i1 = 1.f / (wave_sum64(p1) + 1e-16f);
        float i2 = 1.f / (wave_sum64(p2) + 1e-16f);
        pl[w][0 * 68 + lane] = p0 * i0;
        pl[w][1 * 68 + lane] = p1 * i1;
        pl[w][2 * 68 + lane] = p2 * i2;
        reinterpret_cast<int*>(&pl[w][204])[lane] = sv * 10;
        const float* pt = &pl[w][h * 68];
        const int* zt = reinterpret_cast<const int*>(&pl[w][204]);

        float acc = 0.f;
        int i = 0;
        // two half-waves process edges (i+hf, i+2+hf, ...) 4-deep
        for (; i + 8 <= deg; i += 8) {
            float vv[4], aa[4];
#pragma unroll
            for (int j = 0; j < 4; j++) {
                int e = i + 2 * j + hf;
                int zo = zt[e];
                vv[j] = feat[zo + k];
                aa[j] = pt[e];
            }
#pragma unroll
            for (int j = 0; j < 4; j++) acc += aa[j] * vv[j];
        }
        for (; i < deg; i += 2) {
            int e = i + hf;
            if (e < deg) {
                int zo = zt[e];
                acc += pt[e] * feat[zo + k];
            }
        }
        acc += __shfl_xor(acc, 32);
        if (lane < 30) y1[(size_t)wid * 30 + lane] = acc;
    } else {
        // fallback (deg > 64)
        float ern[3] = {erv.x, erv.y, erv.z};
        float m[3] = {-3.402823466e38f, -3.402823466e38f, -3.402823466e38f};
        for (int i = lane; i < deg; i += 64) {
            int sv = ssrc[s0 + i];
            float4 elv = el[sv];
            float vv[3] = {elv.x, elv.y, elv.z};
#pragma unroll
            for (int hh = 0; hh < 3; hh++) {
                float v = vv[hh] + ern[hh];
                v = v > 0.f ? v : NEG_SLOPE * v;
                m[hh] = fmaxf(m[hh], v);
            }
        }
#pragma unroll
        for (int hh = 0; hh < 3; hh++) m[hh] = wave_max64(m[hh]);
        float s[3] = {};
        for (int i = lane; i < deg; i += 64) {
            int sv = ssrc[s0 + i];
            float4 elv = el[sv];
            float vv[3] = {elv.x, elv.y, elv.z};
#pragma unroll
            for (int hh = 0; hh < 3; hh++) {
                float v = vv[hh] + ern[hh];
                v = v > 0.f ? v : NEG_SLOPE * v;
                s[hh] += __expf(v - m[hh]);
            }
        }
#pragma unroll
        for (int hh = 0; hh < 3; hh++) s[hh] = 1.f / (wave_sum64(s[hh]) + 1e-16f);
        float acc = 0.f;
        for (int i = 0; i < deg; i++) {
            int sv = ssrc[s0 + i];
            float4 elv = el[sv];
            float vv[3] = {elv.x, elv.y, elv.z};
            float v = vv[h] + ern[h];
            v = v > 0.f ? v : NEG_SLOPE * v;
            float a = __expf(v - m[h]) * s[h];
            acc += a * feat[sv * 10 + k];
        }
        if (lane < 30) y1[(size_t)wid * 30 + lane] = acc;
    }
}

// ---------------- xform1: x1 = ReLU(y1_h @ W1_h) (bf16), fused el2/er2 ----------------

__global__ __launch_bounds__(256) void k_xform1(const float* __restrict__ y1,
                                                const float* __restrict__ W1,
                                                const float* __restrict__ val2,
                                                const float* __restrict__ var2,
                                                unsigned short* __restrict__ x1,
                                                float4* __restrict__ el2,
                                                float4* __restrict__ er2, int n) {
    __shared__ float sW[960], sv2[288], sr2[288];
    for (int i = threadIdx.x; i < 960; i += 256) sW[i] = W1[i];
    for (int i = threadIdx.x; i < 288; i += 256) { sv2[i] = val2[i]; sr2[i] = var2[i]; }
    __syncthreads();
    int nd = blockIdx.x * 256 + threadIdx.x;
    if (nd >= n) return;
    float y[30];
#pragma unroll
    for (int i = 0; i < 30; i++) y[i] = y1[(size_t)nd * 30 + i];
    float el[3] = {}, er[3] = {};
#pragma unroll
    for (int h = 0; h < 3; h++) {
#pragma unroll
        for (int d0 = 0; d0 < 32; d0 += 4) {
            ushort4 o;
            unsigned short* op = &o.x;
#pragma unroll
            for (int q = 0; q < 4; q++) {
                int c = h * 32 + d0 + q;
                float acc = 0.f;
#pragma unroll
                for (int k = 0; k < 10; k++) acc += y[h * 10 + k] * sW[k * 96 + c];
                float r = fmaxf(acc, 0.f);   // ReLU
                op[q] = f2bf(r);
#pragma unroll
                for (int hh = 0; hh < 3; hh++) {
                    el[hh] += r * sv2[hh * 96 + c];
                    er[hh] += r * sr2[hh * 96 + c];
                }
            }
            *reinterpret_cast<ushort4*>(&x1[(size_t)nd * 96 + h * 32 + d0]) = o;
        }
    }
    el2[nd] = make_float4(el[0], el[1], el[2], 0.f);
    er2[nd] = make_float4(er[0], er[1], er[2], 0.f);
}

// ---------------- agg2': y2[n][3][96] (bf16) = sum_e alpha2 * x1[src] ----------------

__global__ __launch_bounds__(256) void k_agg2(const unsigned short* __restrict__ x1,
                                              const float4* __restrict__ el,
                                              const float4* __restrict__ er,
                                              const int* __restrict__ row_start,
                                              const int* __restrict__ ssrc,
                                              unsigned short* __restrict__ y2, int n) {
    __shared__ float pl[4][272];
    int wid = (blockIdx.x * blockDim.x + threadIdx.x) >> 6;
    int lane = threadIdx.x & 63;
    int w = threadIdx.x >> 6;
    if (wid >= n) return;
    int s0 = row_start[wid];
    int deg = row_start[wid + 1] - s0;
    int c0 = lane < 48 ? lane * 2 : 0;
    if (deg <= 0) {
        if (lane < 48) {
#pragma unroll
            for (int h = 0; h < 3; h++)
                *reinterpret_cast<ushort2*>(&y2[(size_t)wid * 288 + h * 96 + c0]) =
                    make_ushort2(0, 0);
        }
        return;
    }
    float4 erv = er[wid];
    float acc[3][2] = {};

    if (deg <= 64) {
        bool act = lane < deg;
        int sv = act ? ssrc[s0 + lane] : 0;
        float4 elv = el[sv];
        float v0 = elv.x + erv.x; v0 = v0 > 0.f ? v0 : NEG_SLOPE * v0;
        float v1 = elv.y + erv.y; v1 = v1 > 0.f ? v1 : NEG_SLOPE * v1;
        float v2 = elv.z + erv.z; v2 = v2 > 0.f ? v2 : NEG_SLOPE * v2;
        if (!act) { v0 = -3.402823466e38f; v1 = v0; v2 = v0; }
        float m0 = wave_max64(v0), m1 = wave_max64(v1), m2 = wave_max64(v2);
        float p0 = act ? __expf(v0 - m0) : 0.f;
        float p1 = act ? __expf(v1 - m1) : 0.f;
        float p2 = act ? __expf(v2 - m2) : 0.f;
        float i0 = 1.f / (wave_sum64(p0) + 1e-16f);
        float i1 = 1.f / (wave_sum64(p1) + 1e-16f);
        float i2 = 1.f / (wave_sum64(p2) + 1e-16f);
        pl[w][0 * 68 + lane] = p0 * i0;
        pl[w][1 * 68 + lane] = p1 * i1;
        pl[w][2 * 68 + lane] = p2 * i2;
        reinterpret_cast<int*>(&pl[w][204])[lane] = sv * 96;
        const float* pt0 = &pl[w][0];
        const float* pt1 = &pl[w][68];
        const float* pt2 = &pl[w][136];
        const int* zt = reinterpret_cast<const int*>(&pl[w][204]);
        const unsigned short* zc = x1 + c0;

        int i = 0;
        for (; i + 8 <= deg; i += 8) {
            int zo[8];
#pragma unroll
            for (int j = 0; j < 8; j++) zo[j] = zt[i + j];
            unsigned int r[8];
#pragma unroll
            for (int j = 0; j < 8; j++)
                r[j] = *reinterpret_cast<const unsigned int*>(zc + zo[j]);
#pragma unroll
            for (int j = 0; j < 8; j++) {
                float lo = bflo(r[j]), hi = bfhi(r[j]);
                float a0 = pt0[i + j], a1 = pt1[i + j], a2 = pt2[i + j];
                acc[0][0] += a0 * lo; acc[0][1] += a0 * hi;
                acc[1][0] += a1 * lo; acc[1][1] += a1 * hi;
                acc[2][0] += a2 * lo; acc[2][1] += a2 * hi;
            }
        }
        for (; i < deg; i++) {
            unsigned int r = *reinterpret_cast<const unsigned int*>(zc + zt[i]);
            float lo = bflo(r), hi = bfhi(r);
            float a0 = pt0[i], a1 = pt1[i], a2 = pt2[i];
            acc[0][0] += a0 * lo; acc[0][1] += a0 * hi;
            acc[1][0] += a1 * lo; acc[1][1] += a1 * hi;
            acc[2][0] += a2 * lo; acc[2][1] += a2 * hi;
        }
    } else {
        // fallback (deg > 64)
        float ern[3] = {erv.x, erv.y, erv.z};
        float m[3] = {-3.402823466e38f, -3.402823466e38f, -3.402823466e38f};
        for (int i = lane; i < deg; i += 64) {
            int sv = ssrc[s0 + i];
            float4 elv = el[sv];
            float vv[3] = {elv.x, elv.y, elv.z};
#pragma unroll
            for (int hh = 0; hh < 3; hh++) {
                float v = vv[hh] + ern[hh];
                v = v > 0.f ? v : NEG_SLOPE * v;
                m[hh] = fmaxf(m[hh], v);
            }
        }
#pragma unroll
        for (int hh = 0; hh < 3; hh++) m[hh] = wave_max64(m[hh]);
        float s[3] = {};
        for (int i = lane; i < deg; i += 64) {
            int sv = ssrc[s0 + i];
            float4 elv = el[sv];
            float vv[3] = {elv.x, elv.y, elv.z};
#pragma unroll
            for (int hh = 0; hh < 3; hh++) {
                float v = vv[hh] + ern[hh];
                v = v > 0.f ? v : NEG_SLOPE * v;
                s[hh] += __expf(v - m[hh]);
            }
        }
#pragma unroll
        for (int hh = 0; hh < 3; hh++) s[hh] = 1.f / (wave_sum64(s[hh]) + 1e-16f);
        for (int i = 0; i < deg; i++) {
            int sv = ssrc[s0 + i];
            float4 elv = el[sv];
            float vv[3] = {elv.x, elv.y, elv.z};
            float a[3];
#pragma unroll
            for (int hh = 0; hh < 3; hh++) {
                float v = vv[hh] + ern[hh];
                v = v > 0.f ? v : NEG_SLOPE * v;
                a[hh] = __expf(v - m[hh]) * s[hh];
            }
            unsigned int r = *reinterpret_cast<const unsigned int*>(x1 + sv * 96 + c0);
            float lo = bflo(r), hi = bfhi(r);
            acc[0][0] += a[0] * lo; acc[0][1] += a[0] * hi;
            acc[1][0] += a[1] * lo; acc[1][1] += a[1] * hi;
            acc[2][0] += a[2] * lo; acc[2][1] += a[2] * hi;
        }
    }
    if (lane < 48) {
#pragma unroll
        for (int h = 0; h < 3; h++) {
            ushort2 o2;
            o2.x = f2bf(acc[h][0]); o2.y = f2bf(acc[h][1]);
            *reinterpret_cast<ushort2*>(&y2[(size_t)wid * 288 + h * 96 + c0]) = o2;
        }
    }
}

// ---------------- xform2 (MFMA): x2 = ReLU(y2_h @ W2_h) (bf16) ----------------

__global__ __launch_bounds__(256) void k_xform2(const unsigned short* __restrict__ y2,
                                                const unsigned short* __restrict__ W2T,
                                                unsigned short* __restrict__ x2, int n) {
    int h = blockIdx.y;
    int w = threadIdx.x >> 6;
    int l = threadIdx.x & 63;
    int q = l >> 4, c16 = l & 15;
    int Ra = blockIdx.x * 64 + w * 16 + c16;
    short8v afr[3];
    if (Ra < n) {
#pragma unroll
        for (int ks = 0; ks < 3; ks++)
            afr[ks] = *reinterpret_cast<const short8v*>(y2 + (size_t)Ra * 288 + h * 96 +
                                                        ks * 32 + q * 8);
    } else {
#pragma unroll
        for (int ks = 0; ks < 3; ks++)
#pragma unroll
            for (int i = 0; i < 8; i++) afr[ks][i] = 0;
    }
    f32x4 acc[4];
#pragma unroll
    for (int t = 0; t < 4; t++)
#pragma unroll
        for (int r = 0; r < 4; r++) acc[t][r] = 0.f;
#pragma unroll
    for (int t = 0; t < 4; t++) {
        const unsigned short* bp = W2T + (size_t)(h * 64 + t * 16 + c16) * 96 + q * 8;
#pragma unroll
        for (int ks = 0; ks < 3; ks++) {
            short8v bfr = *reinterpret_cast<const short8v*>(bp + ks * 32);
            acc[t] = __builtin_amdgcn_mfma_f32_16x16x32_bf16(afr[ks], bfr, acc[t], 0, 0, 0);
        }
    }
    int Rq = blockIdx.x * 64 + w * 16 + q * 4;
#pragma unroll
    for (int t = 0; t < 4; t++) {
#pragma unroll
        for (int r = 0; r < 4; r++) {
            if (Rq + r < n)
                x2[(size_t)(Rq + r) * 192 + h * 64 + t * 16 + c16] =
                    f2bf(fmaxf(acc[t][r], 0.f));   // ReLU
        }
    }
}

// ---------------- graph mean-pool (graph_ids sorted): 32-node chunks ----------------

__global__ __launch_bounds__(192) void k_pool(const unsigned short* __restrict__ x2,
                                              const int* __restrict__ gid,
                                              float* __restrict__ gsum, int n) {
    int base = blockIdx.x * 32;
    if (base >= n) return;
    int end = base + 32; if (end > n) end = n;
    int c = threadIdx.x;
    float acc = 0.f;
    int gprev = gid[base];
    for (int i = base; i < end; i++) {
        int g = gid[i];
        if (g != gprev) {
            atomicAdd(&gsum[gprev * 192 + c], acc);
            acc = 0.f;
            gprev = g;
        }
        acc += bf2f(x2[(size_t)i * 192 + c]);
    }
    atomicAdd(&gsum[gprev * 192 + c], acc);
}

// ---------------- MLP head ----------------

__global__ __launch_bounds__(64) void k_head(const float* __restrict__ gsum,
                                             const int* __restrict__ gid,
                                             const float* __restrict__ d1w,
                                             const float* __restrict__ d1b,
                                             const float* __restrict__ d2w,
                                             const float* __restrict__ d2b,
                                             float* __restrict__ out, int n, int G) {
    int g = blockIdx.x, j = threadIdx.x;
    int lo0 = 0, hi0 = n;
    while (lo0 < hi0) { int mid = (lo0 + hi0) >> 1; if (gid[mid] < g) lo0 = mid + 1; else hi0 = mid; }
    int lo1 = lo0, hi1 = n;
    while (lo1 < hi1) { int mid = (lo1 + hi1) >> 1; if (gid[mid] < g + 1) lo1 = mid + 1; else hi1 = mid; }
    float inv = 1.f / fmaxf((float)(lo1 - lo0), 1.f);
    float h = d1b[j];
    for (int k = 0; k < 192; k++) h += (gsum[g * 192 + k] * inv) * d1w[(size_t)k * 64 + j];
    h = fmaxf(h, 0.f);
    float v = h * d2w[j];
    for (int o = 32; o; o >>= 1) v += __shfl_xor(v, o);
    if (j == 0) out[g] = v + d2b[0];
}

// ---------------- launch ----------------

extern "C" void kernel_launch(void* const* d_in, const int* in_sizes, int n_in,
                              void* d_out, int out_size, void* d_ws, size_t ws_size,
                              hipStream_t stream) {
    const float* feat = (const float*)d_in[0];
    const int* src = (const int*)d_in[1];
    const int* dst = (const int*)d_in[2];
    const int* gid = (const int*)d_in[3];
    const float* W1 = (const float*)d_in[4];
    const float* al1 = (const float*)d_in[5];
    const float* ar1 = (const float*)d_in[6];
    const float* W2 = (const float*)d_in[7];
    const float* al2 = (const float*)d_in[8];
    const float* ar2 = (const float*)d_in[9];
    const float* d1w = (const float*)d_in[10];
    const float* d1b = (const float*)d_in[11];
    const float* d2w = (const float*)d_in[12];
    const float* d2b = (const float*)d_in[13];
    float* out = (float*)d_out;
    const int N = in_sizes[0] / 10;   // 50000
    const int E = in_sizes[1];        // 800000
    const int G = out_size;           // 128
    const int NB = (N + 255) / 256;   // 196

    char* p = (char*)d_ws;
    auto take = [&](size_t bytes) -> char* {
        char* r = p;
        p += (bytes + 255) & ~(size_t)255;
        return r;
    };
    float* y1 = (float*)take((size_t)N * 30 * 4);                    // 6MB
    unsigned short* x1 = (unsigned short*)take((size_t)N * 96 * 2);  // 9.6MB
    unsigned short* y2 = (unsigned short*)take((size_t)N * 288 * 2); // 28.8MB
    unsigned short* x2 = (unsigned short*)take((size_t)N * 192 * 2); // 19.2MB
    float4* el1 = (float4*)take((size_t)N * 16);
    float4* er1 = (float4*)take((size_t)N * 16);
    float4* el2 = (float4*)take((size_t)N * 16);
    float4* er2 = (float4*)take((size_t)N * 16);
    unsigned short* W2T = (unsigned short*)take((size_t)96 * 192 * 2);
    float* val2 = (float*)take((size_t)288 * 4);
    float* var2 = (float*)take((size_t)288 * 4);
    int* rank = (int*)take((size_t)E * 4);
    int* bsum = (int*)take((size_t)NB * 4);
    int* bpre = (int*)take((size_t)NB * 4);
    size_t zbytes = (size_t)N * 4 + (size_t)G * 192 * 4;  // deg | gsum
    int* deg = (int*)take(zbytes);
    float* gsum = (float*)(deg + N);
    int* row_start = (int*)take((size_t)(N + 1) * 4);
    int* ssrc = (int*)take((size_t)E * 4);

    hipMemsetAsync(deg, 0, zbytes, stream);

    // hist + rank + W2T/val2/var2 prep
    k_hist<<<(E + 255) / 256, 256, 0, stream>>>(dst, deg, rank, E, W2, al2, ar2,
                                                W2T, val2, var2);
    // el1/er1 from feat
    k_el1<<<NB, 256, 0, stream>>>(feat, W1, al1, ar1, el1, er1, N);
    // CSR: scan + atomic-free scatter
    k_scan1<<<NB, 256, 0, stream>>>(deg, bsum, N);
    k_scan2<<<1, 256, 0, stream>>>(bsum, bpre, row_start, NB, N);
    k_scan3<<<NB, 256, 0, stream>>>(deg, bpre, row_start, N);
    k_scatter<<<(E + 255) / 256, 256, 0, stream>>>(dst, src, rank, row_start, ssrc, E);

    // Layer 1: aggregate feat, then transform
    k_agg1<<<((size_t)N * 64 + 255) / 256, 256, 0, stream>>>(feat, el1, er1, row_start,
                                                             ssrc, y1, N);
    k_xform1<<<NB, 256, 0, stream>>>(y1, W1, val2, var2, x1, el2, er2, N);
    // Layer 2: aggregate x1, then transform (MFMA)
    k_agg2<<<((size_t)N * 64 + 255) / 256, 256, 0, stream>>>(x1, el2, er2, row_start,
                                                             ssrc, y2, N);
    k_xform2<<<dim3((N + 63) / 64, 3), 256, 0, stream>>>(y2, W2T, x2, N);
    // Pool + head
    k_pool<<<(N + 31) / 32, 192, 0, stream>>>(x2, gid, gsum, N);
    k_head<<<G, 64, 0, stream>>>(gsum, gid, d1w, d1b, d2w, d2b, out, N, G);
}

// Round 15
// 264.194 us; speedup vs baseline: 1.0860x; 1.0460x over previous
//
#include <hip/hip_runtime.h>
#include <hip/hip_bf16.h>

#define NEG_SLOPE 0.2f
#define HCHUNK 8192  // edges per histogram block (power of 2; e>>13 recovers block id)

typedef __attribute__((ext_vector_type(8))) short short8v;
typedef __attribute__((ext_vector_type(4))) float f32x4;

__device__ __forceinline__ float wave_max64(float v) {
    for (int o = 32; o; o >>= 1) v = fmaxf(v, __shfl_xor(v, o));
    return v;
}
__device__ __forceinline__ float wave_sum64(float v) {
    for (int o = 32; o; o >>= 1) v += __shfl_xor(v, o);
    return v;
}
__device__ __forceinline__ unsigned short f2bf(float f) {
    unsigned int u = __float_as_uint(f);
    unsigned int r = (u + 0x7fffu + ((u >> 16) & 1u)) >> 16;
    return (unsigned short)r;
}
__device__ __forceinline__ float bf2f(unsigned short u) {
    return __uint_as_float(((unsigned int)u) << 16);
}
__device__ __forceinline__ float bflo(unsigned int pk) {
    return __uint_as_float(pk << 16);
}
__device__ __forceinline__ float bfhi(unsigned int pk) {
    return __uint_as_float(pk & 0xFFFF0000u);
}

// ---------------- LDS-privatized histogram: 2x16-bit packed counters ----------------

__global__ __launch_bounds__(1024) void k_hist2(const int* __restrict__ dst,
                                                unsigned int* __restrict__ blkcnt,
                                                int* __restrict__ rank, int E, int n) {
    __shared__ unsigned int cnt[25000];  // 100KB: nodes 2i (lo16), 2i+1 (hi16)
    int nw = (n + 1) >> 1;
    for (int i = threadIdx.x; i < nw; i += 1024) cnt[i] = 0;
    __syncthreads();
    int base = blockIdx.x * HCHUNK;
#pragma unroll
    for (int i = 0; i < HCHUNK / 1024; i++) {
        int e = base + i * 1024 + threadIdx.x;
        if (e < E) {
            int d = dst[e];
            unsigned int add = (d & 1) ? 0x10000u : 1u;
            unsigned int old = atomicAdd(&cnt[d >> 1], add);
            rank[e] = (d & 1) ? (int)(old >> 16) : (int)(old & 0xFFFFu);
        }
    }
    __syncthreads();
    unsigned int* outp = blkcnt + (size_t)blockIdx.x * nw;
    for (int i = threadIdx.x; i < nw; i += 1024) outp[i] = cnt[i];
}

// ---------------- column scan over blocks: boff (exclusive), deg, bsum (fused scan1) ----

__global__ __launch_bounds__(256) void k_colscan(const unsigned int* __restrict__ blkcnt,
                                                 unsigned short* __restrict__ boff,
                                                 int* __restrict__ deg,
                                                 int* __restrict__ bsum, int n, int NBH) {
    int nd = blockIdx.x * 256 + threadIdx.x;
    int nw = (n + 1) >> 1;
    int run = 0;
    if (nd < n) {
        int w = nd >> 1, sh = (nd & 1) * 16;
#pragma unroll 4
        for (int b = 0; b < NBH; b++) {
            unsigned int c = (blkcnt[(size_t)b * nw + w] >> sh) & 0xFFFFu;
            boff[(size_t)b * n + nd] = (unsigned short)run;
            run += (int)c;
        }
        deg[nd] = run;
    }
    int v = (nd < n) ? run : 0;
    for (int o = 32; o; o >>= 1) v += __shfl_xor(v, o);
    __shared__ int ws[4];
    if ((threadIdx.x & 63) == 0) ws[threadIdx.x >> 6] = v;
    __syncthreads();
    if (threadIdx.x == 0) bsum[blockIdx.x] = ws[0] + ws[1] + ws[2] + ws[3];
}

// ---------------- scan2/scan3: block-prefix + per-node exclusive scan ----------------

__global__ __launch_bounds__(256) void k_scan2(const int* __restrict__ bsum,
                                               int* __restrict__ bpre,
                                               int* __restrict__ row_start,
                                               int nb, int n) {
    __shared__ int s[256];
    int t = threadIdx.x;
    int v = t < nb ? bsum[t] : 0;
    s[t] = v;
    __syncthreads();
    for (int o = 1; o < 256; o <<= 1) {
        int u = (t >= o) ? s[t - o] : 0;
        __syncthreads();
        s[t] += u;
        __syncthreads();
    }
    if (t < nb) bpre[t] = s[t] - v;
    if (t == 255) row_start[n] = s[255];
}

__global__ __launch_bounds__(256) void k_scan3(const int* __restrict__ deg,
                                               const int* __restrict__ bpre,
                                               int* __restrict__ row_start, int n) {
    int idx = blockIdx.x * 256 + threadIdx.x;
    int lane = threadIdx.x & 63;
    int w = threadIdx.x >> 6;
    int d = idx < n ? deg[idx] : 0;
    int x = d;
    for (int o = 1; o < 64; o <<= 1) {
        int u = __shfl_up(x, o);
        if (lane >= o) x += u;
    }
    __shared__ int ws[4];
    if (lane == 63) ws[w] = x;
    __syncthreads();
    int add = bpre[blockIdx.x];
    for (int i = 0; i < w; i++) add += ws[i];
    if (idx < n) row_start[idx] = add + x - d;
}

// ---------------- scatter (atomic-free: row_start + per-block offset + local rank) ----

__global__ void k_scatter(const int* __restrict__ dst, const int* __restrict__ src,
                          const int* __restrict__ rank,
                          const unsigned short* __restrict__ boff,
                          const int* __restrict__ row_start,
                          int* __restrict__ ssrc, int E, int n) {
    int e = blockIdx.x * blockDim.x + threadIdx.x;
    if (e < E) {
        int d = dst[e];
        int b = e >> 13;  // HCHUNK = 8192
        int pos = row_start[d] + (int)boff[(size_t)b * n + d] + rank[e];
        ssrc[pos] = src[e];
    }
}

// ---------------- prep: W2T bf16 transpose + val2/var2 folded vectors ----------------

__global__ __launch_bounds__(256) void k_prep(const float* __restrict__ W2,
                                              const float* __restrict__ al2,
                                              const float* __restrict__ ar2,
                                              unsigned short* __restrict__ W2T,
                                              float* __restrict__ val2,
                                              float* __restrict__ var2) {
    int idx = blockIdx.x * 256 + threadIdx.x;
    if (idx < 96 * 192) {
        int c = idx / 96, k = idx - c * 96;
        W2T[idx] = f2bf(W2[k * 192 + c]);
    } else if (idx < 96 * 192 + 2 * 288) {
        int t = idx - 96 * 192;
        int which = t / 288;
        int tt = t - which * 288;
        int h = tt / 96, j = tt - h * 96;
        const float* av = which ? ar2 : al2;
        float a = 0.f;
        for (int d = 0; d < 64; d++) a += W2[j * 192 + h * 64 + d] * av[h * 64 + d];
        (which ? var2 : val2)[tt] = a;
    }
}

// ---------------- el1/er1 = feat @ (W1_h . al1_h) ----------------

__global__ __launch_bounds__(256) void k_el1(const float* __restrict__ feat,
                                             const float* __restrict__ W1,
                                             const float* __restrict__ al,
                                             const float* __restrict__ ar,
                                             float4* __restrict__ el1,
                                             float4* __restrict__ er1, int n) {
    __shared__ float sW[960], sal[96], sar[96], sval[30], svar[30];
    for (int i = threadIdx.x; i < 960; i += 256) sW[i] = W1[i];
    for (int i = threadIdx.x; i < 96; i += 256) { sal[i] = al[i]; sar[i] = ar[i]; }
    __syncthreads();
    int t = threadIdx.x;
    if (t < 30) {
        int h = t / 10, k = t - h * 10;
        float a = 0.f, b = 0.f;
        for (int d = 0; d < 32; d++) {
            float wv = sW[k * 96 + h * 32 + d];
            a += wv * sal[h * 32 + d];
            b += wv * sar[h * 32 + d];
        }
        sval[t] = a; svar[t] = b;
    }
    __syncthreads();
    int nd = blockIdx.x * 256 + t;
    if (nd >= n) return;
    float x[10];
#pragma unroll
    for (int k = 0; k < 10; k++) x[k] = feat[(size_t)nd * 10 + k];
    float el[3] = {}, er[3] = {};
#pragma unroll
    for (int h = 0; h < 3; h++)
#pragma unroll
        for (int k = 0; k < 10; k++) {
            el[h] += x[k] * sval[h * 10 + k];
            er[h] += x[k] * svar[h * 10 + k];
        }
    el1[nd] = make_float4(el[0], el[1], el[2], 0.f);
    er1[nd] = make_float4(er[0], er[1], er[2], 0.f);
}

// ---------------- agg1': y1[n][3][10] = sum_e alpha1 * feat[src] ----------------

__global__ __launch_bounds__(256) void k_agg1(const float* __restrict__ feat,
                                              const float4* __restrict__ el,
                                              const float4* __restrict__ er,
                                              const int* __restrict__ row_start,
                                              const int* __restrict__ ssrc,
                                              float* __restrict__ y1, int n) {
    __shared__ float pl[4][272];
    int wid = (blockIdx.x * blockDim.x + threadIdx.x) >> 6;
    int lane = threadIdx.x & 63;
    int w = threadIdx.x >> 6;
    if (wid >= n) return;
    int s0 = row_start[wid];
    int deg = row_start[wid + 1] - s0;
    if (deg <= 0) {
        if (lane < 30) y1[(size_t)wid * 30 + lane] = 0.f;
        return;
    }
    float4 erv = er[wid];
    int ll = lane & 31, hf = lane >> 5;
    int h = ll / 10, k = ll - (ll / 10) * 10;
    if (ll >= 30) { h = 2; k = 9; }

    if (deg <= 64) {
        bool act = lane < deg;
        int sv = act ? ssrc[s0 + lane] : 0;
        float4 elv = el[sv];
        float v0 = elv.x + erv.x; v0 = v0 > 0.f ? v0 : NEG_SLOPE * v0;
        float v1 = elv.y + erv.y; v1 = v1 > 0.f ? v1 : NEG_SLOPE * v1;
        float v2 = elv.z + erv.z; v2 = v2 > 0.f ? v2 : NEG_SLOPE * v2;
        if (!act) { v0 = -3.402823466e38f; v1 = v0; v2 = v0; }
        float m0 = wave_max64(v0), m1 = wave_max64(v1), m2 = wave_max64(v2);
        float p0 = act ? __expf(v0 - m0) : 0.f;
        float p1 = act ? __expf(v1 - m1) : 0.f;
        float p2 = act ? __expf(v2 - m2) : 0.f;
        float i0 = 1.f / (wave_sum64(p0) + 1e-16f);
        float i1 = 1.f / (wave_sum64(p1) + 1e-16f);
        float i2 = 1.f / (wave_sum64(p2) + 1e-16f);
        pl[w][0 * 68 + lane] = p0 * i0;
        pl[w][1 * 68 + lane] = p1 * i1;
        pl[w][2 * 68 + lane] = p2 * i2;
        reinterpret_cast<int*>(&pl[w][204])[lane] = sv * 10;
        const float* pt = &pl[w][h * 68];
        const int* zt = reinterpret_cast<const int*>(&pl[w][204]);

        float acc = 0.f;
        int i = 0;
        for (; i + 8 <= deg; i += 8) {
            float vv[4], aa[4];
#pragma unroll
            for (int j = 0; j < 4; j++) {
                int e = i + 2 * j + hf;
                int zo = zt[e];
                vv[j] = feat[zo + k];
                aa[j] = pt[e];
            }
#pragma unroll
            for (int j = 0; j < 4; j++) acc += aa[j] * vv[j];
        }
        for (; i < deg; i += 2) {
            int e = i + hf;
            if (e < deg) {
                int zo = zt[e];
                acc += pt[e] * feat[zo + k];
            }
        }
        acc += __shfl_xor(acc, 32);
        if (lane < 30) y1[(size_t)wid * 30 + lane] = acc;
    } else {
        float ern[3] = {erv.x, erv.y, erv.z};
        float m[3] = {-3.402823466e38f, -3.402823466e38f, -3.402823466e38f};
        for (int i = lane; i < deg; i += 64) {
            int sv = ssrc[s0 + i];
            float4 elv = el[sv];
            float vv[3] = {elv.x, elv.y, elv.z};
#pragma unroll
            for (int hh = 0; hh < 3; hh++) {
                float v = vv[hh] + ern[hh];
                v = v > 0.f ? v : NEG_SLOPE * v;
                m[hh] = fmaxf(m[hh], v);
            }
        }
#pragma unroll
        for (int hh = 0; hh < 3; hh++) m[hh] = wave_max64(m[hh]);
        float s[3] = {};
        for (int i = lane; i < deg; i += 64) {
            int sv = ssrc[s0 + i];
            float4 elv = el[sv];
            float vv[3] = {elv.x, elv.y, elv.z};
#pragma unroll
            for (int hh = 0; hh < 3; hh++) {
                float v = vv[hh] + ern[hh];
                v = v > 0.f ? v : NEG_SLOPE * v;
                s[hh] += __expf(v - m[hh]);
            }
        }
#pragma unroll
        for (int hh = 0; hh < 3; hh++) s[hh] = 1.f / (wave_sum64(s[hh]) + 1e-16f);
        float acc = 0.f;
        for (int i = 0; i < deg; i++) {
            int sv = ssrc[s0 + i];
            float4 elv = el[sv];
            float vv[3] = {elv.x, elv.y, elv.z};
            float v = vv[h] + ern[h];
            v = v > 0.f ? v : NEG_SLOPE * v;
            float a = __expf(v - m[h]) * s[h];
            acc += a * feat[sv * 10 + k];
        }
        if (lane < 30) y1[(size_t)wid * 30 + lane] = acc;
    }
}

// ---------------- xform1: x1 = ReLU(y1_h @ W1_h) (bf16), fused el2/er2 ----------------

__global__ __launch_bounds__(256) void k_xform1(const float* __restrict__ y1,
                                                const float* __restrict__ W1,
                                                const float* __restrict__ val2,
                                                const float* __restrict__ var2,
                                                unsigned short* __restrict__ x1,
                                                float4* __restrict__ el2,
                                                float4* __restrict__ er2, int n) {
    __shared__ float sW[960], sv2[288], sr2[288];
    for (int i = threadIdx.x; i < 960; i += 256) sW[i] = W1[i];
    for (int i = threadIdx.x; i < 288; i += 256) { sv2[i] = val2[i]; sr2[i] = var2[i]; }
    __syncthreads();
    int nd = blockIdx.x * 256 + threadIdx.x;
    if (nd >= n) return;
    float y[30];
#pragma unroll
    for (int i = 0; i < 30; i++) y[i] = y1[(size_t)nd * 30 + i];
    float el[3] = {}, er[3] = {};
#pragma unroll
    for (int h = 0; h < 3; h++) {
#pragma unroll
        for (int d0 = 0; d0 < 32; d0 += 4) {
            ushort4 o;
            unsigned short* op = &o.x;
#pragma unroll
            for (int q = 0; q < 4; q++) {
                int c = h * 32 + d0 + q;
                float acc = 0.f;
#pragma unroll
                for (int k = 0; k < 10; k++) acc += y[h * 10 + k] * sW[k * 96 + c];
                float r = fmaxf(acc, 0.f);
                op[q] = f2bf(r);
#pragma unroll
                for (int hh = 0; hh < 3; hh++) {
                    el[hh] += r * sv2[hh * 96 + c];
                    er[hh] += r * sr2[hh * 96 + c];
                }
            }
            *reinterpret_cast<ushort4*>(&x1[(size_t)nd * 96 + h * 32 + d0]) = o;
        }
    }
    el2[nd] = make_float4(el[0], el[1], el[2], 0.f);
    er2[nd] = make_float4(er[0], er[1], er[2], 0.f);
}

// ---------------- agg2': y2[n][3][96] (bf16) = sum_e alpha2 * x1[src] ----------------

__global__ __launch_bounds__(256) void k_agg2(const unsigned short* __restrict__ x1,
                                              const float4* __restrict__ el,
                                              const float4* __restrict__ er,
                                              const int* __restrict__ row_start,
                                              const int* __restrict__ ssrc,
                                              unsigned short* __restrict__ y2, int n) {
    __shared__ float pl[4][272];
    int wid = (blockIdx.x * blockDim.x + threadIdx.x) >> 6;
    int lane = threadIdx.x & 63;
    int w = threadIdx.x >> 6;
    if (wid >= n) return;
    int s0 = row_start[wid];
    int deg = row_start[wid + 1] - s0;
    int c0 = lane < 48 ? lane * 2 : 0;
    if (deg <= 0) {
        if (lane < 48) {
#pragma unroll
            for (int h = 0; h < 3; h++)
                *reinterpret_cast<ushort2*>(&y2[(size_t)wid * 288 + h * 96 + c0]) =
                    make_ushort2(0, 0);
        }
        return;
    }
    float4 erv = er[wid];
    float acc[3][2] = {};

    if (deg <= 64) {
        bool act = lane < deg;
        int sv = act ? ssrc[s0 + lane] : 0;
        float4 elv = el[sv];
        float v0 = elv.x + erv.x; v0 = v0 > 0.f ? v0 : NEG_SLOPE * v0;
        float v1 = elv.y + erv.y; v1 = v1 > 0.f ? v1 : NEG_SLOPE * v1;
        float v2 = elv.z + erv.z; v2 = v2 > 0.f ? v2 : NEG_SLOPE * v2;
        if (!act) { v0 = -3.402823466e38f; v1 = v0; v2 = v0; }
        float m0 = wave_max64(v0), m1 = wave_max64(v1), m2 = wave_max64(v2);
        float p0 = act ? __expf(v0 - m0) : 0.f;
        float p1 = act ? __expf(v1 - m1) : 0.f;
        float p2 = act ? __expf(v2 - m2) : 0.f;
        float i0 = 1.f / (wave_sum64(p0) + 1e-16f);
        float i1 = 1.f / (wave_sum64(p1) + 1e-16f);
        float i2 = 1.f / (wave_sum64(p2) + 1e-16f);
        pl[w][0 * 68 + lane] = p0 * i0;
        pl[w][1 * 68 + lane] = p1 * i1;
        pl[w][2 * 68 + lane] = p2 * i2;
        reinterpret_cast<int*>(&pl[w][204])[lane] = sv * 96;
        const float* pt0 = &pl[w][0];
        const float* pt1 = &pl[w][68];
        const float* pt2 = &pl[w][136];
        const int* zt = reinterpret_cast<const int*>(&pl[w][204]);
        const unsigned short* zc = x1 + c0;

        int i = 0;
        for (; i + 8 <= deg; i += 8) {
            int zo[8];
#pragma unroll
            for (int j = 0; j < 8; j++) zo[j] = zt[i + j];
            unsigned int r[8];
#pragma unroll
            for (int j = 0; j < 8; j++)
                r[j] = *reinterpret_cast<const unsigned int*>(zc + zo[j]);
#pragma unroll
            for (int j = 0; j < 8; j++) {
                float lo = bflo(r[j]), hi = bfhi(r[j]);
                float a0 = pt0[i + j], a1 = pt1[i + j], a2 = pt2[i + j];
                acc[0][0] += a0 * lo; acc[0][1] += a0 * hi;
                acc[1][0] += a1 * lo; acc[1][1] += a1 * hi;
                acc[2][0] += a2 * lo; acc[2][1] += a2 * hi;
            }
        }
        for (; i < deg; i++) {
            unsigned int r = *reinterpret_cast<const unsigned int*>(zc + zt[i]);
            float lo = bflo(r), hi = bfhi(r);
            float a0 = pt0[i], a1 = pt1[i], a2 = pt2[i];
            acc[0][0] += a0 * lo; acc[0][1] += a0 * hi;
            acc[1][0] += a1 * lo; acc[1][1] += a1 * hi;
            acc[2][0] += a2 * lo; acc[2][1] += a2 * hi;
        }
    } else {
        float ern[3] = {erv.x, erv.y, erv.z};
        float m[3] = {-3.402823466e38f, -3.402823466e38f, -3.402823466e38f};
        for (int i = lane; i < deg; i += 64) {
            int sv = ssrc[s0 + i];
            float4 elv = el[sv];
            float vv[3] = {elv.x, elv.y, elv.z};
#pragma unroll
            for (int hh = 0; hh < 3; hh++) {
                float v = vv[hh] + ern[hh];
                v = v > 0.f ? v : NEG_SLOPE * v;
                m[hh] = fmaxf(m[hh], v);
            }
        }
#pragma unroll
        for (int hh = 0; hh < 3; hh++) m[hh] = wave_max64(m[hh]);
        float s[3] = {};
        for (int i = lane; i < deg; i += 64) {
            int sv = ssrc[s0 + i];
            float4 elv = el[sv];
            float vv[3] = {elv.x, elv.y, elv.z};
#pragma unroll
            for (int hh = 0; hh < 3; hh++) {
                float v = vv[hh] + ern[hh];
                v = v > 0.f ? v : NEG_SLOPE * v;
                s[hh] += __expf(v - m[hh]);
            }
        }
#pragma unroll
        for (int hh = 0; hh < 3; hh++) s[hh] = 1.f / (wave_sum64(s[hh]) + 1e-16f);
        for (int i = 0; i < deg; i++) {
            int sv = ssrc[s0 + i];
            float4 elv = el[sv];
            float vv[3] = {elv.x, elv.y, elv.z};
            float a[3];
#pragma unroll
            for (int hh = 0; hh < 3; hh++) {
                float v = vv[hh] + ern[hh];
                v = v > 0.f ? v : NEG_SLOPE * v;
                a[hh] = __expf(v - m[hh]) * s[hh];
            }
            unsigned int r = *reinterpret_cast<const unsigned int*>(x1 + sv * 96 + c0);
            float lo = bflo(r), hi = bfhi(r);
            acc[0][0] += a[0] * lo; acc[0][1] += a[0] * hi;
            acc[1][0] += a[1] * lo; acc[1][1] += a[1] * hi;
            acc[2][0] += a[2] * lo; acc[2][1] += a[2] * hi;
        }
    }
    if (lane < 48) {
#pragma unroll
        for (int h = 0; h < 3; h++) {
            ushort2 o2;
            o2.x = f2bf(acc[h][0]); o2.y = f2bf(acc[h][1]);
            *reinterpret_cast<ushort2*>(&y2[(size_t)wid * 288 + h * 96 + c0]) = o2;
        }
    }
}

// ---------------- xform2 (MFMA): x2 = ReLU(y2_h @ W2_h) (bf16) ----------------

__global__ __launch_bounds__(256) void k_xform2(const unsigned short* __restrict__ y2,
                                                const unsigned short* __restrict__ W2T,
                                                unsigned short* __restrict__ x2, int n) {
    int h = blockIdx.y;
    int w = threadIdx.x >> 6;
    int l = threadIdx.x & 63;
    int q = l >> 4, c16 = l & 15;
    int Ra = blockIdx.x * 64 + w * 16 + c16;
    short8v afr[3];
    if (Ra < n) {
#pragma unroll
        for (int ks = 0; ks < 3; ks++)
            afr[ks] = *reinterpret_cast<const short8v*>(y2 + (size_t)Ra * 288 + h * 96 +
                                                        ks * 32 + q * 8);
    } else {
#pragma unroll
        for (int ks = 0; ks < 3; ks++)
#pragma unroll
            for (int i = 0; i < 8; i++) afr[ks][i] = 0;
    }
    f32x4 acc[4];
#pragma unroll
    for (int t = 0; t < 4; t++)
#pragma unroll
        for (int r = 0; r < 4; r++) acc[t][r] = 0.f;
#pragma unroll
    for (int t = 0; t < 4; t++) {
        const unsigned short* bp = W2T + (size_t)(h * 64 + t * 16 + c16) * 96 + q * 8;
#pragma unroll
        for (int ks = 0; ks < 3; ks++) {
            short8v bfr = *reinterpret_cast<const short8v*>(bp + ks * 32);
            acc[t] = __builtin_amdgcn_mfma_f32_16x16x32_bf16(afr[ks], bfr, acc[t], 0, 0, 0);
        }
    }
    int Rq = blockIdx.x * 64 + w * 16 + q * 4;
#pragma unroll
    for (int t = 0; t < 4; t++) {
#pragma unroll
        for (int r = 0; r < 4; r++) {
            if (Rq + r < n)
                x2[(size_t)(Rq + r) * 192 + h * 64 + t * 16 + c16] =
                    f2bf(fmaxf(acc[t][r], 0.f));
        }
    }
}

// ---------------- graph mean-pool (graph_ids sorted): 32-node chunks ----------------

__global__ __launch_bounds__(192) void k_pool(const unsigned short* __restrict__ x2,
                                              const int* __restrict__ gid,
                                              float* __restrict__ gsum, int n) {
    int base = blockIdx.x * 32;
    if (base >= n) return;
    int end = base + 32; if (end > n) end = n;
    int c = threadIdx.x;
    float acc = 0.f;
    int gprev = gid[base];
    for (int i = base; i < end; i++) {
        int g = gid[i];
        if (g != gprev) {
            atomicAdd(&gsum[gprev * 192 + c], acc);
            acc = 0.f;
            gprev = g;
        }
        acc += bf2f(x2[(size_t)i * 192 + c]);
    }
    atomicAdd(&gsum[gprev * 192 + c], acc);
}

// ---------------- MLP head ----------------

__global__ __launch_bounds__(64) void k_head(const float* __restrict__ gsum,
                                             const int* __restrict__ gid,
                                             const float* __restrict__ d1w,
                                             const float* __restrict__ d1b,
                                             const float* __restrict__ d2w,
                                             const float* __restrict__ d2b,
                                             float* __restrict__ out, int n, int G) {
    int g = blockIdx.x, j = threadIdx.x;
    int lo0 = 0, hi0 = n;
    while (lo0 < hi0) { int mid = (lo0 + hi0) >> 1; if (gid[mid] < g) lo0 = mid + 1; else hi0 = mid; }
    int lo1 = lo0, hi1 = n;
    while (lo1 < hi1) { int mid = (lo1 + hi1) >> 1; if (gid[mid] < g + 1) lo1 = mid + 1; else hi1 = mid; }
    float inv = 1.f / fmaxf((float)(lo1 - lo0), 1.f);
    float h = d1b[j];
    for (int k = 0; k < 192; k++) h += (gsum[g * 192 + k] * inv) * d1w[(size_t)k * 64 + j];
    h = fmaxf(h, 0.f);
    float v = h * d2w[j];
    for (int o = 32; o; o >>= 1) v += __shfl_xor(v, o);
    if (j == 0) out[g] = v + d2b[0];
}

// ---------------- launch ----------------

extern "C" void kernel_launch(void* const* d_in, const int* in_sizes, int n_in,
                              void* d_out, int out_size, void* d_ws, size_t ws_size,
                              hipStream_t stream) {
    const float* feat = (const float*)d_in[0];
    const int* src = (const int*)d_in[1];
    const int* dst = (const int*)d_in[2];
    const int* gid = (const int*)d_in[3];
    const float* W1 = (const float*)d_in[4];
    const float* al1 = (const float*)d_in[5];
    const float* ar1 = (const float*)d_in[6];
    const float* W2 = (const float*)d_in[7];
    const float* al2 = (const float*)d_in[8];
    const float* ar2 = (const float*)d_in[9];
    const float* d1w = (const float*)d_in[10];
    const float* d1b = (const float*)d_in[11];
    const float* d2w = (const float*)d_in[12];
    const float* d2b = (const float*)d_in[13];
    float* out = (float*)d_out;
    const int N = in_sizes[0] / 10;   // 50000
    const int E = in_sizes[1];        // 800000
    const int G = out_size;           // 128
    const int NB = (N + 255) / 256;   // 196
    const int NBH = (E + HCHUNK - 1) / HCHUNK;  // 98

    char* p = (char*)d_ws;
    auto take = [&](size_t bytes) -> char* {
        char* r = p;
        p += (bytes + 255) & ~(size_t)255;
        return r;
    };
    float* y1 = (float*)take((size_t)N * 30 * 4);                    // 6MB
    unsigned short* x1 = (unsigned short*)take((size_t)N * 96 * 2);  // 9.6MB
    unsigned short* y2 = (unsigned short*)take((size_t)N * 288 * 2); // 28.8MB
    unsigned short* x2 = (unsigned short*)take((size_t)N * 192 * 2); // 19.2MB
    float4* el1 = (float4*)take((size_t)N * 16);
    float4* er1 = (float4*)take((size_t)N * 16);
    float4* el2 = (float4*)take((size_t)N * 16);
    float4* er2 = (float4*)take((size_t)N * 16);
    unsigned short* W2T = (unsigned short*)take((size_t)96 * 192 * 2);
    float* val2 = (float*)take((size_t)288 * 4);
    float* var2 = (float*)take((size_t)288 * 4);
    int* rank = (int*)take((size_t)E * 4);
    unsigned int* blkcnt = (unsigned int*)take((size_t)NBH * ((N + 1) / 2) * 4);  // 9.8MB
    unsigned short* boff = (unsigned short*)take((size_t)NBH * N * 2);            // 9.8MB
    int* deg = (int*)take((size_t)N * 4);
    int* bsum = (int*)take((size_t)NB * 4);
    int* bpre = (int*)take((size_t)NB * 4);
    float* gsum = (float*)take((size_t)G * 192 * 4);
    int* row_start = (int*)take((size_t)(N + 1) * 4);
    int* ssrc = (int*)take((size_t)E * 4);

    hipMemsetAsync(gsum, 0, (size_t)G * 192 * 4, stream);

    // CSR build: LDS-privatized histogram -> column scan -> block scan -> scatter
    k_hist2<<<NBH, 1024, 0, stream>>>(dst, blkcnt, rank, E, N);
    k_prep<<<(96 * 192 + 2 * 288 + 255) / 256, 256, 0, stream>>>(W2, al2, ar2,
                                                                 W2T, val2, var2);
    k_el1<<<NB, 256, 0, stream>>>(feat, W1, al1, ar1, el1, er1, N);
    k_colscan<<<NB, 256, 0, stream>>>(blkcnt, boff, deg, bsum, N, NBH);
    k_scan2<<<1, 256, 0, stream>>>(bsum, bpre, row_start, NB, N);
    k_scan3<<<NB, 256, 0, stream>>>(deg, bpre, row_start, N);
    k_scatter<<<(E + 255) / 256, 256, 0, stream>>>(dst, src, rank, boff, row_start,
                                                   ssrc, E, N);

    // Layer 1: aggregate feat, then transform
    k_agg1<<<((size_t)N * 64 + 255) / 256, 256, 0, stream>>>(feat, el1, er1, row_start,
                                                             ssrc, y1, N);
    k_xform1<<<NB, 256, 0, stream>>>(y1, W1, val2, var2, x1, el2, er2, N);
    // Layer 2: aggregate x1, then transform (MFMA)
    k_agg2<<<((size_t)N * 64 + 255) / 256, 256, 0, stream>>>(x1, el2, er2, row_start,
                                                             ssrc, y2, N);
    k_xform2<<<dim3((N + 63) / 64, 3), 256, 0, stream>>>(y2, W2T, x2, N);
    // Pool + head
    k_pool<<<(N + 31) / 32, 192, 0, stream>>>(x2, gid, gsum, N);
    k_head<<<G, 64, 0, stream>>>(gsum, gid, d1w, d1b, d2w, d2b, out, N, G);
}